// Round 12
// baseline (261.914 us; speedup 1.0000x reference)
//
#include <hip/hip_runtime.h>
#include <hip/hip_bf16.h>
#include <math.h>

// CrossAttention fused pipeline, bf16 MFMA everywhere.
// B=64, N=256, C=1024, H=16, hd=64, sem=768, M=B*N=16384.
// R12: prep split into two self-balancing grid-stride kernels —
// k_prep_w (tables+bias+transposes, 512 blocks) and k_prep_c (pure
// fp32->bf16 convert stream, 2048 blocks). Unmixes the fat 5-way loop body
// so the 168MB convert runs as a clean stream, while keeping grid-stride's
// automatic balance (R7's block-range sectioning destroyed it).
// GEMM/attn byte-identical to R11 (verified 252.66us).

typedef unsigned int uint;
typedef __attribute__((ext_vector_type(4)))  short s16x4;
typedef __attribute__((ext_vector_type(8)))  short s16x8;
typedef __attribute__((ext_vector_type(4)))  float f32x4;
typedef __attribute__((ext_vector_type(16))) float f32x16;

#define AS1 __attribute__((address_space(1)))
#define AS3 __attribute__((address_space(3)))

__device__ __forceinline__ short f2bf(float x){
  union{float f;uint u;}v; v.f=x;
  return (short)((v.u + 0x7FFFu + ((v.u>>16)&1u))>>16);   // RNE
}
__device__ __forceinline__ float bf2f(short s){
  union{float f;uint u;}v; v.u=((uint)(unsigned short)s)<<16; return v.f;
}
__device__ __forceinline__ uint packbf(float a,float b){
  return (uint)(unsigned short)f2bf(a) | ((uint)(unsigned short)f2bf(b)<<16);
}
__device__ __forceinline__ void gl_lds16(const void* g, void* l){
  __builtin_amdgcn_global_load_lds((const AS1 uint*)g, (AS3 uint*)l, 16, 0, 0);
}
__device__ __forceinline__ s16x8 ld16(const short* p){ return *(const s16x8*)p; }

// Dtype detect: bits[14:7] of packed words are bf16 exponents (~99% in
// [120,130] for N(0,1)) vs fp32 mantissa bits (~4%). All blocks scan the
// SAME 8KB q-window (L2-hit) -> identical deterministic flag.
__device__ __forceinline__ int detect_dtype(const uint* qw){
  __shared__ int cnt;
  if(threadIdx.x==0) cnt=0;
  __syncthreads();
  int c=0;
  for(int i=threadIdx.x;i<2048;i+=256){
    uint e=(qw[i]>>7)&0xFFu;
    if(e>=120u && e<=130u) c++;
  }
  atomicAdd(&cnt,c);
  __syncthreads();
  return (cnt>1024)?0:1;                  // 0 = bf16, 1 = fp32
}

// ---------------- prep A: tables + bias + weight transposes (+flag publish)
__global__ void k_prep_w(const void* Wq, const void* Wkv, const void* Wp,
                         const void* bsrc, const void* qsrc,
                         short* WqT, short* WkvT, short* WpT, float* biasF,
                         float* cosT, float* sinT, int* flag){
  const int f=detect_dtype((const uint*)qsrc);
  if(threadIdx.x==0 && blockIdx.x==0) *flag=f;

  const long T0=16384, T1=T0+1024, T2=T1+131072, T3=T2+196608, T4=T3+131072;
  const long stride=(long)gridDim.x*blockDim.x;
  for(long idx=(long)blockIdx.x*blockDim.x+threadIdx.x; idx<T4; idx+=stride){
    if(idx<T0){                       // RoPE tables (f64 to match numpy)
      int t=(int)idx, n=t>>6, d=t&63;
      int i=n>>4, j=n&15, p=(d&31)>>1;
      double fr=pow(10000.0, -(double)(2*p)/32.0);
      double tt=(d<32)?(double)i:(double)j;
      double a=tt*fr;
      cosT[t]=(float)cos(a); sinT[t]=(float)sin(a);
    } else if(idx<T1){                // bias -> f32
      int t=(int)(idx-T0);
      biasF[t]= f ? ((const float*)bsrc)[t] : bf2f(((const short*)bsrc)[t]);
    } else {                          // weight transposes (KxN -> NxK bf16)
      const void* W; short* WT; int K,Nn; long g;
      if(idx<T2){ W=Wq;  WT=WqT;  K=1024; Nn=1024; g=idx-T1; }
      else if(idx<T3){ W=Wkv; WT=WkvT; K=768; Nn=2048; g=idx-T2; }
      else { W=Wp;  WT=WpT;  K=1024; Nn=1024; g=idx-T3; }
      int n=(int)(g%Nn); int k0=(int)(g/Nn)*8;
      s16x8 o;
      #pragma unroll
      for(int j=0;j<8;j++){
        o[j]= f ? f2bf(((const float*)W)[(long)(k0+j)*Nn+n])
                : ((const short*)W)[(long)(k0+j)*Nn+n];
      }
      *(s16x8*)&WT[(long)n*K+k0]=o;
    }
  }
}

// ---------------- prep B: pure activation convert stream (fp32 -> bf16 x8)
__global__ void k_prep_c(const void* qsrc, const void* kvsrc,
                         short* qbf, short* kvbf){
  const int f=detect_dtype((const uint*)qsrc);
  if(!f) return;                          // bf16 inputs: gemm reads raw buffers
  const long NQ=2097152, NTOT=NQ+1572864; // 16B-groups: q 32MB, kv 24MB
  const long stride=(long)gridDim.x*blockDim.x;
  for(long i=(long)blockIdx.x*blockDim.x+threadIdx.x; i<NTOT; i+=stride){
    const float4* s; short* dst; long j;
    if(i<NQ){ s=(const float4*)qsrc;  dst=qbf;  j=i; }
    else    { s=(const float4*)kvsrc; dst=kvbf; j=i-NQ; }
    float4 a=s[j*2], b=s[j*2+1];
    s16x8 o;
    o[0]=f2bf(a.x);o[1]=f2bf(a.y);o[2]=f2bf(a.z);o[3]=f2bf(a.w);
    o[4]=f2bf(b.x);o[5]=f2bf(b.y);o[6]=f2bf(b.z);o[7]=f2bf(b.w);
    ((s16x8*)dst)[j]=o;
  }
}

// ---------------- 8-phase GEMM (32x32x16 MFMA), fused epilogues -------------
// Tile 256x256, BK=64, 512 threads = 8 waves (2Mx4N), wave owns 128x64 =
// 4x2 frags of 32x32. LDS 128KiB = 2dbuf x {A,B} x 2half x (128x64 bf16).
// Swizzle: 16B slot s of row r holds chunk s^((r>>1)&7) (involution, both
// sides). Per phase: {ds_read subtile || stage half-tile; BAR; lgkm0; 8 MFMA;
// BAR}. vmcnt(4) once per K-tile. MODE 0 = merged QKV with chunk-local role
// split (per-XCD round 1 = q, rounds 2-3 = kv -> role-pure L2 residency);
// A-panel base selected at runtime: original input when flag==0 (bf16).
// MODE 1 = proj (+bias -> d_out).
#define BAR   __builtin_amdgcn_s_barrier()
#define LGKM0 asm volatile("s_waitcnt lgkmcnt(0)" ::: "memory")
#define VMC4  asm volatile("s_waitcnt vmcnt(4)" ::: "memory")
#define PRIO1 __builtin_amdgcn_s_setprio(1)
#define PRIO0 __builtin_amdgcn_s_setprio(0)

#define MM(H,V,BR) do{ \
  _Pragma("unroll") for(int ks_=0;ks_<4;ks_++){ \
    _Pragma("unroll") for(int mf_=0;mf_<2;mf_++){ \
      acc[(H)*2+mf_][V]=__builtin_amdgcn_mfma_f32_32x32x16_bf16( \
        aR[mf_][ks_],BR[ks_],acc[(H)*2+mf_][V],0,0,0); \
  }} }while(0)

#define HALFIT(BUF,TA,TB) do{ \
  const short* RA=&lds[BUF][0][wm][0]; \
  const short* RB=&lds[BUF][1][0][0]; \
  ldA(RA,0,aR); ldB(RB,0,bR0); stage(0,0,TA); \
  BAR; LGKM0; PRIO1; MM(0,0,bR0); PRIO0; BAR; \
  ldB(RB,1,bR1); stage(0,1,TA); \
  BAR; LGKM0; PRIO1; MM(0,1,bR1); PRIO0; BAR; \
  ldA(RA,1,aR); stage(1,0,TB); \
  BAR; LGKM0; PRIO1; MM(1,1,bR1); PRIO0; BAR; \
  stage(1,1,TB); \
  BAR; PRIO1; MM(1,0,bR0); PRIO0; VMC4; BAR; \
}while(0)

template<int MODE>
__launch_bounds__(512,2)
__global__ void k_gemm8(const short* __restrict__ Aq, const short* __restrict__ Bq,
                        const short* __restrict__ Akv, const short* __restrict__ Bkv,
                        const short* __restrict__ qraw, const short* __restrict__ kvraw,
                        short* __restrict__ out0, short* __restrict__ out1,
                        short* __restrict__ out2,
                        const float* __restrict__ cosT, const float* __restrict__ sinT,
                        const float* __restrict__ bias, const int* __restrict__ flag,
                        void* __restrict__ dout){
  __shared__ __align__(16) short lds[2][2][2][8192];  // [dbuf][A/B][half][128*64]
  const int tid=threadIdx.x, lane=tid&63, wave=tid>>6;
  const int ln31=lane&31, l5=lane>>5;
  const int wm=wave>>2, wn=wave&3;
  const int fl=*flag;
  int role, tm, tn, Kdim;
  const short *Ag, *Bg;
  if(MODE==1){
    // XCD-aware bijective block swizzle (nwg=256, %8==0)
    const int nwg=gridDim.x, cpx=nwg>>3;
    const int wg=((int)blockIdx.x&7)*cpx+((int)blockIdx.x>>3);
    role=2; tn=wg&3; tm=wg>>2; Kdim=1024;
    Ag=Aq+(long)tm*256*1024; Bg=Bq+(long)tn*256*1024;
  } else {
    // chunk-local role split: XCD = bid&7, pos = bid>>3 (0..95).
    // pos<32 -> q (round 1, role-pure); else kv (rounds 2-3).
    const int xcd=(int)blockIdx.x&7, pos=(int)blockIdx.x>>3;
    const short* Aq_e  = fl? Aq  : qraw;    // bf16 inputs: read original buffer
    const short* Akv_e = fl? Akv : kvraw;
    if(pos<32){ role=0; int qi=xcd*32+pos; tn=qi&3; tm=qi>>2; Kdim=1024;
      Ag=Aq_e+(long)tm*256*1024; Bg=Bq+(long)tn*256*1024; }
    else { role=1; int ki=xcd*64+(pos-32); tn=ki&7; tm=ki>>3; Kdim=768;
      Ag=Akv_e+(long)tm*256*768; Bg=Bkv+(long)tn*256*768; }
  }
  const int NT=Kdim>>6;
  f32x16 acc[4][2]={};
  s16x8 aR[2][4], bR0[4], bR1[4];

  auto stage=[&](int op,int hf,int kt){
    int ktw=(kt>=NT)?kt-NT:kt;               // tail wrap, memory-safe
    const short* G=(op? Bg:Ag)+((long)(hf*128))*Kdim+ktw*64;
    short* R=&lds[kt&1][op][hf][0];          // NT even -> parity preserved
    #pragma unroll
    for(int l=0;l<2;l++){
      int lr=l*64+wave*8+(lane>>3);
      int c=(lane&7)^((lr>>1)&7);            // pre-swizzled global source
      gl_lds16(G+(long)lr*Kdim+c*8, R+l*4096+wave*512+lane*8);
    }
  };
  auto ldA=[&](const short* R,int h,s16x8 (&a)[2][4]){
    #pragma unroll
    for(int mf=0;mf<2;mf++){
      int lr=h*64+mf*32+ln31;
      int sw=(lr>>1)&7;
      #pragma unroll
      for(int ks=0;ks<4;ks++){
        int slot=(ks*2+l5)^sw;
        a[mf][ks]=*(const s16x8*)&R[lr*64+slot*8];
      }
    }
  };
  auto ldB=[&](const short* R0,int v,s16x8 (&b)[4]){
    int row=wn*64+v*32+ln31;
    const short* R=R0+(row>>7)*8192;
    int lr=row&127;
    int sw=(lr>>1)&7;
    #pragma unroll
    for(int ks=0;ks<4;ks++){
      int slot=(ks*2+l5)^sw;
      b[ks]=*(const s16x8*)&R[lr*64+slot*8];
    }
  };

  // prologue: T0.B, T0.A, T1.B staged; wait all but last 4 -> T0 resident
  stage(1,0,0); stage(1,1,0); stage(0,0,0); stage(0,1,0);
  stage(1,0,1); stage(1,1,1);
  VMC4;
  BAR;

  for(int t=0;t<NT;t+=2){
    HALFIT(0, t+1, t+2);
    HALFIT(1, t+2, t+3);
  }

  // ---------------- epilogue (32x32 C/D: col=lane&31, row=(r&3)+8*(r>>2)+4*l5)
  const int mb=tm*256+wm*128, nb=tn*256+wn*64;
  #pragma unroll
  for(int mf=0;mf<4;mf++)
  #pragma unroll
  for(int nf=0;nf<2;nf++){
    const int n=nb+nf*32+ln31;
    if(MODE==1){
      float bi=bias[n];
      #pragma unroll
      for(int r=0;r<16;r++){
        int m=mb+mf*32+(r&3)+8*(r>>2)+4*l5;
        float o=acc[mf][nf][r]+bi;
        long idx=((long)m<<10)+n;
        if(fl) ((float*)dout)[idx]=o;
        else   ((short*)dout)[idx]=f2bf(o);
      }
    } else if(role==0){
      int h=n>>6, d=n&63;
      #pragma unroll
      for(int r=0;r<16;r++){
        int m=mb+mf*32+(r&3)+8*(r>>2)+4*l5;
        int b=m>>8, nn=m&255;
        float v=acc[mf][nf][r];
        float part=__shfl_xor(v,1);
        float c=cosT[(nn<<6)+d], s=sinT[(nn<<6)+d];
        float rot=(d&1)?part:-part;
        out0[(((long)(b*16+h)*256+nn)<<6)+d]=f2bf((v*c+rot*s)*0.125f);
      }
    } else {
      if(n<1024){   // uniform per block (tn<4): K-head with RoPE
        int h=(n>>6)&15, d=n&63;
        #pragma unroll
        for(int r=0;r<16;r++){
          int m=mb+mf*32+(r&3)+8*(r>>2)+4*l5;
          int b=m>>8, nn=m&255;
          float v=acc[mf][nf][r];
          float part=__shfl_xor(v,1);
          float c=cosT[(nn<<6)+d], s=sinT[(nn<<6)+d];
          float rot=(d&1)?part:-part;
          out1[(((long)(b*16+h)*256+nn)<<6)+d]=f2bf(v*c+rot*s);
        }
      }else{        // V, written pre-transposed (B,H,64,256)
        int h=(n>>6)&15, d=n&63;
        #pragma unroll
        for(int rq=0;rq<4;rq++){
          int m0=mb+mf*32+8*rq+4*l5;
          int b=m0>>8, nn0=m0&255;
          s16x4 pk;
          #pragma unroll
          for(int j=0;j<4;j++) pk[j]=f2bf(acc[mf][nf][rq*4+j]);
          *(s16x4*)&out2[(((long)(b*16+h)*64+d)<<8)+nn0]=pk;
        }
      }
    }
  }
}

// ---------------- attention: 1 block per (b,h), 4 waves x 64 q-rows ---------
// Swapped QK^T: ST = mfma(K,Q) => D[kv=(l>>4)*4+r][q=l&15]; softmax per q is
// lane-local + 2 shfl_xor. P^T redistribution to the PV B-operand goes via a
// wave-private LDS region (aliasing ol): lane (g,c) writes pairs
// P[q=qb*16+c][{g*2, g*2+1, 8+g*2, 8+g*2+1}], then reads its B-fragment as
// one ds_read_b128 at P[q][g*4] (row stride 20 u32 -> 16B-aligned, <=2-way
// banks = free). Same-wave write->read: lgkmcnt only, no barrier.
// PV: O^T = mfma(VT, P^T) => D[d=(l>>4)*4+r][q=l&15]. V^T loads issued BEFORE
// QK^T so global latency hides under MFMA+softmax (T14 issue-early).
__launch_bounds__(256,2)
__global__ void k_attn(const short* qh, const short* kb, const short* vt, short* out){
  __shared__ __align__(16) short ol[4][64][72];
  int bh=blockIdx.x, b=bh>>4, h=bh&15;
  int tid=threadIdx.x, lane=tid&63, wave=tid>>6;
  const short* Q=qh+(long)bh*256*64;
  const short* K=kb+(long)bh*256*64;
  const short* VT=vt+(long)bh*64*256;
  uint* P=(uint*)&ol[wave][0][0];          // 64 rows x 20 u32 = 5120B < 9216B

  s16x8 qf[4][2];
  #pragma unroll
  for(int qb=0;qb<4;qb++)
    #pragma unroll
    for(int kk=0;kk<2;kk++)
      qf[qb][kk]=ld16(Q+(wave*64+qb*16+(lane&15))*64+kk*32+(lane>>4)*8);

  f32x4 o[4][4]={};
  float mrow[4]={-INFINITY,-INFINITY,-INFINITY,-INFINITY};
  float srow[4]={0.f,0.f,0.f,0.f};
  const int g=lane>>4, lc=lane&15;

  for(int kt=0;kt<8;kt++){
    s16x8 kA[2][2];
    #pragma unroll
    for(int f=0;f<2;f++)
      #pragma unroll
      for(int kk=0;kk<2;kk++)
        kA[f][kk]=ld16(K+(kt*32+f*16+lc)*64+kk*32+g*8);
    s16x8 vA[4];                       // issue-early: latency hides under QK^T
    #pragma unroll
    for(int db=0;db<4;db++)
      vA[db]=ld16(VT+(db*16+lc)*256+kt*32+g*8);

    f32x4 st[2][4]={};
    PRIO1;
    #pragma unroll
    for(int kk=0;kk<2;kk++)
      #pragma unroll
      for(int f=0;f<2;f++)
        #pragma unroll
        for(int qb=0;qb<4;qb++)
          st[f][qb]=__builtin_amdgcn_mfma_f32_16x16x32_bf16(kA[f][kk],qf[qb][kk],st[f][qb],0,0,0);
    PRIO0;

    #pragma unroll
    for(int qb=0;qb<4;qb++){
      float pm=st[0][qb][0];
      #pragma unroll
      for(int f=0;f<2;f++)
        #pragma unroll
        for(int r=0;r<4;r++) pm=fmaxf(pm,st[f][qb][r]);
      pm=fmaxf(pm,__shfl_xor(pm,16));
      pm=fmaxf(pm,__shfl_xor(pm,32));
      float mn=fmaxf(mrow[qb],pm);
      float al=__expf(mrow[qb]-mn);
      mrow[qb]=mn;
      float p00=__expf(st[0][qb][0]-mn), p01=__expf(st[0][qb][1]-mn);
      float p02=__expf(st[0][qb][2]-mn), p03=__expf(st[0][qb][3]-mn);
      float p10=__expf(st[1][qb][0]-mn), p11=__expf(st[1][qb][1]-mn);
      float p12=__expf(st[1][qb][2]-mn), p13=__expf(st[1][qb][3]-mn);
      float ps=p00+p01+p02+p03+p10+p11+p12+p13;
      ps+=__shfl_xor(ps,16);
      ps+=__shfl_xor(ps,32);
      srow[qb]=srow[qb]*al+ps;
      #pragma unroll
      for(int db=0;db<4;db++){
        o[db][qb][0]*=al; o[db][qb][1]*=al; o[db][qb][2]*=al; o[db][qb][3]*=al;
      }
      // scatter packed P^T pairs: rows g*4+{0..3} (f=0) and 16+g*4+{0..3} (f=1)
      uint* row=&P[(qb*16+lc)*20];
      row[g*2  ]=packbf(p00,p01);
      row[g*2+1]=packbf(p02,p03);
      row[8+g*2  ]=packbf(p10,p11);
      row[8+g*2+1]=packbf(p12,p13);
    }
    asm volatile("s_waitcnt lgkmcnt(0)" ::: "memory");
    s16x8 pb[4];
    #pragma unroll
    for(int qb=0;qb<4;qb++)
      pb[qb]=*(const s16x8*)&P[(qb*16+lc)*20+g*4];
    PRIO1;
    #pragma unroll
    for(int db=0;db<4;db++)
      #pragma unroll
      for(int qb=0;qb<4;qb++)
        o[db][qb]=__builtin_amdgcn_mfma_f32_16x16x32_bf16(vA[db],pb[qb],o[db][qb],0,0,0);
    PRIO0;
  }

  #pragma unroll
  for(int db=0;db<4;db++)
    #pragma unroll
    for(int qb=0;qb<4;qb++)
      #pragma unroll
      for(int r=0;r<4;r++){
        int d=db*16+(lane>>4)*4+r;
        int q=qb*16+(lane&15);
        ol[wave][q][d]=f2bf(o[db][qb][r]/srow[qb]);
      }
  __syncthreads();
  #pragma unroll
  for(int it=0;it<8;it++){
    int q=wave*64+it*8+(lane>>3);
    int cc=lane&7;
    s16x8 x=*(const s16x8*)&ol[wave][it*8+(lane>>3)][cc*8];
    *(s16x8*)&out[((long)(b*256+q)<<10)+h*64+cc*8]=x;
  }
}

// ---------------- host ------------------------------------------------------
extern "C" void kernel_launch(void* const* d_in, const int* in_sizes, int n_in,
                              void* d_out, int out_size, void* d_ws, size_t ws_size,
                              hipStream_t stream){
  const long M=16384;
  char* ws=(char*)d_ws;
  size_t off=0;
  auto alloc=[&](size_t b){ void* p=ws+off; off+=(b+255)&~(size_t)255; return p; };
  int*   flag =(int*)  alloc(256);
  float* cosT =(float*)alloc(256*64*4);
  float* sinT =(float*)alloc(256*64*4);
  float* biasF=(float*)alloc(1024*4);
  short* qbf  =(short*)alloc((size_t)M*1024*2);   // reused as attn_out
  short* kvbf =(short*)alloc((size_t)M*768*2);
  short* WqT  =(short*)alloc((size_t)1024*1024*2);
  short* WkvT =(short*)alloc((size_t)2048*768*2);
  short* WpT  =(short*)alloc((size_t)1024*1024*2);
  short* qhB  =(short*)alloc((size_t)16777216*2);
  short* kbuf =(short*)alloc((size_t)16777216*2);
  short* vtb  =(short*)alloc((size_t)16777216*2);

  k_prep_w<<<512,256,0,stream>>>(d_in[2],d_in[3],d_in[4],d_in[5],d_in[0],
                                 WqT,WkvT,WpT,biasF,cosT,sinT,flag);
  k_prep_c<<<2048,256,0,stream>>>(d_in[0],d_in[1],qbf,kvbf);
  k_gemm8<0><<<768,512,0,stream>>>(qbf,WqT,kvbf,WkvT,
                                   (const short*)d_in[0],(const short*)d_in[1],
                                   qhB,kbuf,vtb,cosT,sinT,biasF,flag,nullptr);
  k_attn<<<1024,256,0,stream>>>(qhB,kbuf,vtb,qbf);
  k_gemm8<1><<<256,512,0,stream>>>(qbf,WpT,nullptr,nullptr,nullptr,nullptr,
                                   nullptr,nullptr,nullptr,
                                   cosT,sinT,biasF,flag,d_out);
}

// Round 13
// 251.055 us; speedup vs baseline: 1.0433x; 1.0433x over previous
//
#include <hip/hip_runtime.h>
#include <hip/hip_bf16.h>
#include <math.h>

// CrossAttention fused pipeline, bf16 MFMA everywhere.
// B=64, N=256, C=1024, H=16, hd=64, sem=768, M=B*N=16384.
// R13: revert R12's prep split (+9us: k_prep_w latency-bound drain blocks
// the convert stream; the single fused grid-stride ladder overlaps them
// for free). Restore R11 byte-for-byte (verified 252.66/252.69us best).

typedef unsigned int uint;
typedef __attribute__((ext_vector_type(4)))  short s16x4;
typedef __attribute__((ext_vector_type(8)))  short s16x8;
typedef __attribute__((ext_vector_type(4)))  float f32x4;
typedef __attribute__((ext_vector_type(16))) float f32x16;

#define AS1 __attribute__((address_space(1)))
#define AS3 __attribute__((address_space(3)))

__device__ __forceinline__ short f2bf(float x){
  union{float f;uint u;}v; v.f=x;
  return (short)((v.u + 0x7FFFu + ((v.u>>16)&1u))>>16);   // RNE
}
__device__ __forceinline__ float bf2f(short s){
  union{float f;uint u;}v; v.u=((uint)(unsigned short)s)<<16; return v.f;
}
__device__ __forceinline__ uint packbf(float a,float b){
  return (uint)(unsigned short)f2bf(a) | ((uint)(unsigned short)f2bf(b)<<16);
}
__device__ __forceinline__ void gl_lds16(const void* g, void* l){
  __builtin_amdgcn_global_load_lds((const AS1 uint*)g, (AS3 uint*)l, 16, 0, 0);
}
__device__ __forceinline__ s16x8 ld16(const short* p){ return *(const s16x8*)p; }

// ---------------- fused prep: detect + tables + bias + transposes + converts
// Dtype flag: bits[14:7] of packed words are bf16 exponents (~99% in
// [120,130] for N(0,1)) vs fp32 mantissa bits (~4%). Every block scans the
// SAME 8KB q-window (L2-hit) -> identical flag; block 0 publishes for later
// kernels. When f==0 (bf16 inputs) the activation converts are SKIPPED:
// k_gemm8 MODE0 reads the original input buffers directly.
__global__ void k_prep(const void* Wq, const void* Wkv, const void* Wp,
                       const void* bsrc, const void* qsrc, const void* kvsrc,
                       short* WqT, short* WkvT, short* WpT, float* biasF,
                       float* cosT, float* sinT, short* qbf, short* kvbf,
                       int* flag){
  __shared__ int cnt;
  const uint* qw=(const uint*)qsrc;
  if(threadIdx.x==0) cnt=0;
  __syncthreads();
  int c=0;
  for(int i=threadIdx.x;i<2048;i+=256){
    uint e=(qw[i]>>7)&0xFFu;
    if(e>=120u && e<=130u) c++;
  }
  atomicAdd(&cnt,c);
  __syncthreads();
  const int f=(cnt>1024)?0:1;             // 0 = bf16, 1 = fp32
  if(threadIdx.x==0 && blockIdx.x==0) *flag=f;

  const long S0=16384, S1=S0+1024, S2=S1+131072, S3=S2+196608, S4=S3+131072,
             S5=S4+2097152, S6=S5+1572864;
  const long lim = f ? S6 : S4;           // bf16 inputs: skip converts entirely
  const long stride=(long)gridDim.x*blockDim.x;
  for(long idx=(long)blockIdx.x*blockDim.x+threadIdx.x; idx<lim; idx+=stride){
    if(idx<S0){                       // RoPE tables (f64 to match numpy)
      int t=(int)idx, n=t>>6, d=t&63;
      int i=n>>4, j=n&15, p=(d&31)>>1;
      double fr=pow(10000.0, -(double)(2*p)/32.0);
      double tt=(d<32)?(double)i:(double)j;
      double a=tt*fr;
      cosT[t]=(float)cos(a); sinT[t]=(float)sin(a);
    } else if(idx<S1){                // bias -> f32
      int t=(int)(idx-S0);
      biasF[t]= f ? ((const float*)bsrc)[t] : bf2f(((const short*)bsrc)[t]);
    } else if(idx<S4){                // weight transposes (KxN -> NxK bf16)
      const void* W; short* WT; int K,Nn; long g;
      if(idx<S2){ W=Wq;  WT=WqT;  K=1024; Nn=1024; g=idx-S1; }
      else if(idx<S3){ W=Wkv; WT=WkvT; K=768; Nn=2048; g=idx-S2; }
      else { W=Wp;  WT=WpT;  K=1024; Nn=1024; g=idx-S3; }
      int n=(int)(g%Nn); int k0=(int)(g/Nn)*8;
      s16x8 o;
      #pragma unroll
      for(int j=0;j<8;j++){
        o[j]= f ? f2bf(((const float*)W)[(long)(k0+j)*Nn+n])
                : ((const short*)W)[(long)(k0+j)*Nn+n];
      }
      *(s16x8*)&WT[(long)n*K+k0]=o;
    } else {                          // activations -> bf16 (only when f==1)
      const void* src; short* dst; long i;
      if(idx<S5){ src=qsrc; dst=qbf; i=idx-S4; }
      else { src=kvsrc; dst=kvbf; i=idx-S5; }
      const float4* s=(const float4*)src;
      float4 a=s[i*2], b=s[i*2+1];
      s16x8 o;
      o[0]=f2bf(a.x);o[1]=f2bf(a.y);o[2]=f2bf(a.z);o[3]=f2bf(a.w);
      o[4]=f2bf(b.x);o[5]=f2bf(b.y);o[6]=f2bf(b.z);o[7]=f2bf(b.w);
      ((s16x8*)dst)[i]=o;
    }
  }
}

// ---------------- 8-phase GEMM (32x32x16 MFMA), fused epilogues -------------
// Tile 256x256, BK=64, 512 threads = 8 waves (2Mx4N), wave owns 128x64 =
// 4x2 frags of 32x32. LDS 128KiB = 2dbuf x {A,B} x 2half x (128x64 bf16).
// Swizzle: 16B slot s of row r holds chunk s^((r>>1)&7) (involution, both
// sides). Per phase: {ds_read subtile || stage half-tile; BAR; lgkm0; 8 MFMA;
// BAR}. vmcnt(4) once per K-tile. MODE 0 = merged QKV with chunk-local role
// split (per-XCD round 1 = q, rounds 2-3 = kv -> role-pure L2 residency);
// A-panel base selected at runtime: original input when flag==0 (bf16).
// MODE 1 = proj (+bias -> d_out).
#define BAR   __builtin_amdgcn_s_barrier()
#define LGKM0 asm volatile("s_waitcnt lgkmcnt(0)" ::: "memory")
#define VMC4  asm volatile("s_waitcnt vmcnt(4)" ::: "memory")
#define PRIO1 __builtin_amdgcn_s_setprio(1)
#define PRIO0 __builtin_amdgcn_s_setprio(0)

#define MM(H,V,BR) do{ \
  _Pragma("unroll") for(int ks_=0;ks_<4;ks_++){ \
    _Pragma("unroll") for(int mf_=0;mf_<2;mf_++){ \
      acc[(H)*2+mf_][V]=__builtin_amdgcn_mfma_f32_32x32x16_bf16( \
        aR[mf_][ks_],BR[ks_],acc[(H)*2+mf_][V],0,0,0); \
  }} }while(0)

#define HALFIT(BUF,TA,TB) do{ \
  const short* RA=&lds[BUF][0][wm][0]; \
  const short* RB=&lds[BUF][1][0][0]; \
  ldA(RA,0,aR); ldB(RB,0,bR0); stage(0,0,TA); \
  BAR; LGKM0; PRIO1; MM(0,0,bR0); PRIO0; BAR; \
  ldB(RB,1,bR1); stage(0,1,TA); \
  BAR; LGKM0; PRIO1; MM(0,1,bR1); PRIO0; BAR; \
  ldA(RA,1,aR); stage(1,0,TB); \
  BAR; LGKM0; PRIO1; MM(1,1,bR1); PRIO0; BAR; \
  stage(1,1,TB); \
  BAR; PRIO1; MM(1,0,bR0); PRIO0; VMC4; BAR; \
}while(0)

template<int MODE>
__launch_bounds__(512,2)
__global__ void k_gemm8(const short* __restrict__ Aq, const short* __restrict__ Bq,
                        const short* __restrict__ Akv, const short* __restrict__ Bkv,
                        const short* __restrict__ qraw, const short* __restrict__ kvraw,
                        short* __restrict__ out0, short* __restrict__ out1,
                        short* __restrict__ out2,
                        const float* __restrict__ cosT, const float* __restrict__ sinT,
                        const float* __restrict__ bias, const int* __restrict__ flag,
                        void* __restrict__ dout){
  __shared__ __align__(16) short lds[2][2][2][8192];  // [dbuf][A/B][half][128*64]
  const int tid=threadIdx.x, lane=tid&63, wave=tid>>6;
  const int ln31=lane&31, l5=lane>>5;
  const int wm=wave>>2, wn=wave&3;
  const int fl=*flag;
  int role, tm, tn, Kdim;
  const short *Ag, *Bg;
  if(MODE==1){
    // XCD-aware bijective block swizzle (nwg=256, %8==0)
    const int nwg=gridDim.x, cpx=nwg>>3;
    const int wg=((int)blockIdx.x&7)*cpx+((int)blockIdx.x>>3);
    role=2; tn=wg&3; tm=wg>>2; Kdim=1024;
    Ag=Aq+(long)tm*256*1024; Bg=Bq+(long)tn*256*1024;
  } else {
    // chunk-local role split: XCD = bid&7, pos = bid>>3 (0..95).
    // pos<32 -> q (round 1, role-pure); else kv (rounds 2-3).
    const int xcd=(int)blockIdx.x&7, pos=(int)blockIdx.x>>3;
    const short* Aq_e  = fl? Aq  : qraw;    // bf16 inputs: read original buffer
    const short* Akv_e = fl? Akv : kvraw;
    if(pos<32){ role=0; int qi=xcd*32+pos; tn=qi&3; tm=qi>>2; Kdim=1024;
      Ag=Aq_e+(long)tm*256*1024; Bg=Bq+(long)tn*256*1024; }
    else { role=1; int ki=xcd*64+(pos-32); tn=ki&7; tm=ki>>3; Kdim=768;
      Ag=Akv_e+(long)tm*256*768; Bg=Bkv+(long)tn*256*768; }
  }
  const int NT=Kdim>>6;
  f32x16 acc[4][2]={};
  s16x8 aR[2][4], bR0[4], bR1[4];

  auto stage=[&](int op,int hf,int kt){
    int ktw=(kt>=NT)?kt-NT:kt;               // tail wrap, memory-safe
    const short* G=(op? Bg:Ag)+((long)(hf*128))*Kdim+ktw*64;
    short* R=&lds[kt&1][op][hf][0];          // NT even -> parity preserved
    #pragma unroll
    for(int l=0;l<2;l++){
      int lr=l*64+wave*8+(lane>>3);
      int c=(lane&7)^((lr>>1)&7);            // pre-swizzled global source
      gl_lds16(G+(long)lr*Kdim+c*8, R+l*4096+wave*512+lane*8);
    }
  };
  auto ldA=[&](const short* R,int h,s16x8 (&a)[2][4]){
    #pragma unroll
    for(int mf=0;mf<2;mf++){
      int lr=h*64+mf*32+ln31;
      int sw=(lr>>1)&7;
      #pragma unroll
      for(int ks=0;ks<4;ks++){
        int slot=(ks*2+l5)^sw;
        a[mf][ks]=*(const s16x8*)&R[lr*64+slot*8];
      }
    }
  };
  auto ldB=[&](const short* R0,int v,s16x8 (&b)[4]){
    int row=wn*64+v*32+ln31;
    const short* R=R0+(row>>7)*8192;
    int lr=row&127;
    int sw=(lr>>1)&7;
    #pragma unroll
    for(int ks=0;ks<4;ks++){
      int slot=(ks*2+l5)^sw;
      b[ks]=*(const s16x8*)&R[lr*64+slot*8];
    }
  };

  // prologue: T0.B, T0.A, T1.B staged; wait all but last 4 -> T0 resident
  stage(1,0,0); stage(1,1,0); stage(0,0,0); stage(0,1,0);
  stage(1,0,1); stage(1,1,1);
  VMC4;
  BAR;

  for(int t=0;t<NT;t+=2){
    HALFIT(0, t+1, t+2);
    HALFIT(1, t+2, t+3);
  }

  // ---------------- epilogue (32x32 C/D: col=lane&31, row=(r&3)+8*(r>>2)+4*l5)
  const int mb=tm*256+wm*128, nb=tn*256+wn*64;
  #pragma unroll
  for(int mf=0;mf<4;mf++)
  #pragma unroll
  for(int nf=0;nf<2;nf++){
    const int n=nb+nf*32+ln31;
    if(MODE==1){
      float bi=bias[n];
      #pragma unroll
      for(int r=0;r<16;r++){
        int m=mb+mf*32+(r&3)+8*(r>>2)+4*l5;
        float o=acc[mf][nf][r]+bi;
        long idx=((long)m<<10)+n;
        if(fl) ((float*)dout)[idx]=o;
        else   ((short*)dout)[idx]=f2bf(o);
      }
    } else if(role==0){
      int h=n>>6, d=n&63;
      #pragma unroll
      for(int r=0;r<16;r++){
        int m=mb+mf*32+(r&3)+8*(r>>2)+4*l5;
        int b=m>>8, nn=m&255;
        float v=acc[mf][nf][r];
        float part=__shfl_xor(v,1);
        float c=cosT[(nn<<6)+d], s=sinT[(nn<<6)+d];
        float rot=(d&1)?part:-part;
        out0[(((long)(b*16+h)*256+nn)<<6)+d]=f2bf((v*c+rot*s)*0.125f);
      }
    } else {
      if(n<1024){   // uniform per block (tn<4): K-head with RoPE
        int h=(n>>6)&15, d=n&63;
        #pragma unroll
        for(int r=0;r<16;r++){
          int m=mb+mf*32+(r&3)+8*(r>>2)+4*l5;
          int b=m>>8, nn=m&255;
          float v=acc[mf][nf][r];
          float part=__shfl_xor(v,1);
          float c=cosT[(nn<<6)+d], s=sinT[(nn<<6)+d];
          float rot=(d&1)?part:-part;
          out1[(((long)(b*16+h)*256+nn)<<6)+d]=f2bf(v*c+rot*s);
        }
      }else{        // V, written pre-transposed (B,H,64,256)
        int h=(n>>6)&15, d=n&63;
        #pragma unroll
        for(int rq=0;rq<4;rq++){
          int m0=mb+mf*32+8*rq+4*l5;
          int b=m0>>8, nn0=m0&255;
          s16x4 pk;
          #pragma unroll
          for(int j=0;j<4;j++) pk[j]=f2bf(acc[mf][nf][rq*4+j]);
          *(s16x4*)&out2[(((long)(b*16+h)*64+d)<<8)+nn0]=pk;
        }
      }
    }
  }
}

// ---------------- attention: 1 block per (b,h), 4 waves x 64 q-rows ---------
// Swapped QK^T: ST = mfma(K,Q) => D[kv=(l>>4)*4+r][q=l&15]; softmax per q is
// lane-local + 2 shfl_xor. P^T redistribution to the PV B-operand goes via a
// wave-private LDS region (aliasing ol): lane (g,c) writes pairs
// P[q=qb*16+c][{g*2, g*2+1, 8+g*2, 8+g*2+1}], then reads its B-fragment as
// one ds_read_b128 at P[q][g*4] (row stride 20 u32 -> 16B-aligned, <=2-way
// banks = free). Same-wave write->read: lgkmcnt only, no barrier.
// PV: O^T = mfma(VT, P^T) => D[d=(l>>4)*4+r][q=l&15]. V^T loads issued BEFORE
// QK^T so global latency hides under MFMA+softmax (T14 issue-early).
__launch_bounds__(256,2)
__global__ void k_attn(const short* qh, const short* kb, const short* vt, short* out){
  __shared__ __align__(16) short ol[4][64][72];
  int bh=blockIdx.x, b=bh>>4, h=bh&15;
  int tid=threadIdx.x, lane=tid&63, wave=tid>>6;
  const short* Q=qh+(long)bh*256*64;
  const short* K=kb+(long)bh*256*64;
  const short* VT=vt+(long)bh*64*256;
  uint* P=(uint*)&ol[wave][0][0];          // 64 rows x 20 u32 = 5120B < 9216B

  s16x8 qf[4][2];
  #pragma unroll
  for(int qb=0;qb<4;qb++)
    #pragma unroll
    for(int kk=0;kk<2;kk++)
      qf[qb][kk]=ld16(Q+(wave*64+qb*16+(lane&15))*64+kk*32+(lane>>4)*8);

  f32x4 o[4][4]={};
  float mrow[4]={-INFINITY,-INFINITY,-INFINITY,-INFINITY};
  float srow[4]={0.f,0.f,0.f,0.f};
  const int g=lane>>4, lc=lane&15;

  for(int kt=0;kt<8;kt++){
    s16x8 kA[2][2];
    #pragma unroll
    for(int f=0;f<2;f++)
      #pragma unroll
      for(int kk=0;kk<2;kk++)
        kA[f][kk]=ld16(K+(kt*32+f*16+lc)*64+kk*32+g*8);
    s16x8 vA[4];                       // issue-early: latency hides under QK^T
    #pragma unroll
    for(int db=0;db<4;db++)
      vA[db]=ld16(VT+(db*16+lc)*256+kt*32+g*8);

    f32x4 st[2][4]={};
    PRIO1;
    #pragma unroll
    for(int kk=0;kk<2;kk++)
      #pragma unroll
      for(int f=0;f<2;f++)
        #pragma unroll
        for(int qb=0;qb<4;qb++)
          st[f][qb]=__builtin_amdgcn_mfma_f32_16x16x32_bf16(kA[f][kk],qf[qb][kk],st[f][qb],0,0,0);
    PRIO0;

    #pragma unroll
    for(int qb=0;qb<4;qb++){
      float pm=st[0][qb][0];
      #pragma unroll
      for(int f=0;f<2;f++)
        #pragma unroll
        for(int r=0;r<4;r++) pm=fmaxf(pm,st[f][qb][r]);
      pm=fmaxf(pm,__shfl_xor(pm,16));
      pm=fmaxf(pm,__shfl_xor(pm,32));
      float mn=fmaxf(mrow[qb],pm);
      float al=__expf(mrow[qb]-mn);
      mrow[qb]=mn;
      float p00=__expf(st[0][qb][0]-mn), p01=__expf(st[0][qb][1]-mn);
      float p02=__expf(st[0][qb][2]-mn), p03=__expf(st[0][qb][3]-mn);
      float p10=__expf(st[1][qb][0]-mn), p11=__expf(st[1][qb][1]-mn);
      float p12=__expf(st[1][qb][2]-mn), p13=__expf(st[1][qb][3]-mn);
      float ps=p00+p01+p02+p03+p10+p11+p12+p13;
      ps+=__shfl_xor(ps,16);
      ps+=__shfl_xor(ps,32);
      srow[qb]=srow[qb]*al+ps;
      #pragma unroll
      for(int db=0;db<4;db++){
        o[db][qb][0]*=al; o[db][qb][1]*=al; o[db][qb][2]*=al; o[db][qb][3]*=al;
      }
      // scatter packed P^T pairs: rows g*4+{0..3} (f=0) and 16+g*4+{0..3} (f=1)
      uint* row=&P[(qb*16+lc)*20];
      row[g*2  ]=packbf(p00,p01);
      row[g*2+1]=packbf(p02,p03);
      row[8+g*2  ]=packbf(p10,p11);
      row[8+g*2+1]=packbf(p12,p13);
    }
    asm volatile("s_waitcnt lgkmcnt(0)" ::: "memory");
    s16x8 pb[4];
    #pragma unroll
    for(int qb=0;qb<4;qb++)
      pb[qb]=*(const s16x8*)&P[(qb*16+lc)*20+g*4];
    PRIO1;
    #pragma unroll
    for(int db=0;db<4;db++)
      #pragma unroll
      for(int qb=0;qb<4;qb++)
        o[db][qb]=__builtin_amdgcn_mfma_f32_16x16x32_bf16(vA[db],pb[qb],o[db][qb],0,0,0);
    PRIO0;
  }

  #pragma unroll
  for(int db=0;db<4;db++)
    #pragma unroll
    for(int qb=0;qb<4;qb++)
      #pragma unroll
      for(int r=0;r<4;r++){
        int d=db*16+(lane>>4)*4+r;
        int q=qb*16+(lane&15);
        ol[wave][q][d]=f2bf(o[db][qb][r]/srow[qb]);
      }
  __syncthreads();
  #pragma unroll
  for(int it=0;it<8;it++){
    int q=wave*64+it*8+(lane>>3);
    int cc=lane&7;
    s16x8 x=*(const s16x8*)&ol[wave][it*8+(lane>>3)][cc*8];
    *(s16x8*)&out[((long)(b*256+q)<<10)+h*64+cc*8]=x;
  }
}

// ---------------- host ------------------------------------------------------
extern "C" void kernel_launch(void* const* d_in, const int* in_sizes, int n_in,
                              void* d_out, int out_size, void* d_ws, size_t ws_size,
                              hipStream_t stream){
  const long M=16384;
  char* ws=(char*)d_ws;
  size_t off=0;
  auto alloc=[&](size_t b){ void* p=ws+off; off+=(b+255)&~(size_t)255; return p; };
  int*   flag =(int*)  alloc(256);
  float* cosT =(float*)alloc(256*64*4);
  float* sinT =(float*)alloc(256*64*4);
  float* biasF=(float*)alloc(1024*4);
  short* qbf  =(short*)alloc((size_t)M*1024*2);   // reused as attn_out
  short* kvbf =(short*)alloc((size_t)M*768*2);
  short* WqT  =(short*)alloc((size_t)1024*1024*2);
  short* WkvT =(short*)alloc((size_t)2048*768*2);
  short* WpT  =(short*)alloc((size_t)1024*1024*2);
  short* qhB  =(short*)alloc((size_t)16777216*2);
  short* kbuf =(short*)alloc((size_t)16777216*2);
  short* vtb  =(short*)alloc((size_t)16777216*2);

  k_prep<<<2048,256,0,stream>>>(d_in[2],d_in[3],d_in[4],d_in[5],d_in[0],d_in[1],
                                WqT,WkvT,WpT,biasF,cosT,sinT,qbf,kvbf,flag);
  k_gemm8<0><<<768,512,0,stream>>>(qbf,WqT,kvbf,WkvT,
                                   (const short*)d_in[0],(const short*)d_in[1],
                                   qhB,kbuf,vtb,cosT,sinT,biasF,flag,nullptr);
  k_attn<<<1024,256,0,stream>>>(qhB,kbuf,vtb,qbf);
  k_gemm8<1><<<256,512,0,stream>>>(qbf,WpT,nullptr,nullptr,nullptr,nullptr,
                                   nullptr,nullptr,nullptr,
                                   cosT,sinT,biasF,flag,d_out);
}